// Round 2
// baseline (52.285 us; speedup 1.0000x reference)
//
#include <hip/hip_runtime.h>
#include <math.h>

#define TT 4096
#define DD 1024
#define NSPAN 8192
#define MW 30
#define WEMB 20
#define VECW (4*DD + WEMB)   // 4116 floats per span row

typedef float nf4 __attribute__((ext_vector_type(4)));

static __device__ __forceinline__ float dot4(const float4 a, const float4 b) {
    return fmaf(a.w, b.w, fmaf(a.z, b.z, fmaf(a.y, b.y, a.x * b.x)));
}
static __device__ __forceinline__ void fma4(float4& acc, const float w, const float4 v) {
    acc.x = fmaf(w, v.x, acc.x); acc.y = fmaf(w, v.y, acc.y);
    acc.z = fmaf(w, v.z, acc.z); acc.w = fmaf(w, v.w, acc.w);
}
static __device__ __forceinline__ void add4(float4& acc, const float4 v) {
    acc.x += v.x; acc.y += v.y; acc.z += v.z; acc.w += v.w;
}
static __device__ __forceinline__ void nstore(const float4 v, float* p) {
    nf4 t = { v.x, v.y, v.z, v.w };
    __builtin_nontemporal_store(t, (nf4*)p);
}

// ---- kernel 1: counting-sort spans by b (1 block, all in LDS) ----
__global__ void __launch_bounds__(1024) sort_kernel(const int* __restrict__ bptr,
                                                    int* __restrict__ perm) {
    const int tid = threadIdx.x;
    __shared__ int h[TT];          // histogram, then running offsets
    __shared__ int wsum[16];
    #pragma unroll
    for (int k = 0; k < 4; ++k) h[tid * 4 + k] = 0;
    __syncthreads();
    #pragma unroll
    for (int k = 0; k < NSPAN / 1024; ++k)
        atomicAdd(&h[bptr[k * 1024 + tid]], 1);
    __syncthreads();
    const int v0 = h[tid*4+0], v1 = h[tid*4+1], v2 = h[tid*4+2], v3 = h[tid*4+3];
    const int s = v0 + v1 + v2 + v3;
    const int lane = tid & 63;
    int incl = s;
    #pragma unroll
    for (int off = 1; off < 64; off <<= 1) {
        int t = __shfl_up(incl, off);
        if (lane >= off) incl += t;
    }
    if (lane == 63) wsum[tid >> 6] = incl;
    __syncthreads();
    if (tid < 16) {
        int ws = wsum[tid];
        #pragma unroll
        for (int off = 1; off < 16; off <<= 1) {
            int t = __shfl_up(ws, off);
            if (tid >= off) ws += t;
        }
        wsum[tid] = ws;
    }
    __syncthreads();
    const int waveoff = (tid >> 6) == 0 ? 0 : wsum[(tid >> 6) - 1];
    int excl = waveoff + (incl - s);
    h[tid*4+0] = excl;  excl += v0;
    h[tid*4+1] = excl;  excl += v1;
    h[tid*4+2] = excl;  excl += v2;
    h[tid*4+3] = excl;
    __syncthreads();
    #pragma unroll
    for (int k = 0; k < NSPAN / 1024; ++k) {
        const int n = k * 1024 + tid;
        const int pos = atomicAdd(&h[bptr[n]], 1);
        perm[pos] = n;
    }
}

// ---- kernel 2: one WAVE per (sorted) span; fused attn-dot, no LDS/syncs ----
// lane l owns float4 slices {l, 64+l, 128+l, 192+l} of every D-row, so each
// load/store instruction covers a contiguous 1 KiB (64 lanes x 16 B).
// attn_b cancels under softmax (shift invariance); |logit| <= ~3 so no
// max-subtraction is needed: w_i = exp2(dot_i * log2e) directly.
// Section float offsets within a span row (VECW = 4116):
//   b_vec 0 | e_vec DD | width_emb 2*DD | head_emb 2*DD+WEMB | span_avg 3*DD+WEMB
#define PROC_ROW(C0, C1, C2, C3) do {                                        \
        float pd = (dot4(C0, w0) + dot4(C1, w1))                             \
                 + (dot4(C2, w2) + dot4(C3, w3));                            \
        pd += __shfl_xor(pd, 32); pd += __shfl_xor(pd, 16);                  \
        pd += __shfl_xor(pd, 8);  pd += __shfl_xor(pd, 4);                   \
        pd += __shfl_xor(pd, 2);  pd += __shfl_xor(pd, 1);                   \
        const float wg = exp2f(pd * 1.44269504f);                            \
        ssum += wg;                                                          \
        fma4(h0, wg, C0); fma4(h1, wg, C1); fma4(h2, wg, C2); fma4(h3, wg, C3); \
        add4(a0, C0); add4(a1, C1); add4(a2, C2); add4(a3, C3);              \
    } while (0)

__global__ void __launch_bounds__(256, 4) span_kernel(
        const float* __restrict__ x,
        const int* __restrict__ bptr,
        const int* __restrict__ eptr,
        const float* __restrict__ embed_w,
        const float* __restrict__ attn_w,
        const int* __restrict__ perm,
        float* __restrict__ out) {
    const int tid = threadIdx.x;
    const int wv  = tid >> 6;          // wave 0..3: which span of this block
    const int l   = tid & 63;          // lane
    // XCD-chunked swizzle: XCD k gets a contiguous 1024-run of sorted spans
    // -> ~512-token window (~2 MB of x) resident in its 4 MB L2.
    const int blk  = (blockIdx.x & 7) * (NSPAN / 4 / 8) + (blockIdx.x >> 3);
    const int spos = blk * 4 + wv;
    const int n    = perm[spos];
    const int b     = bptr[n];
    const int e_raw = eptr[n];
    const int e     = min(e_raw, TT - 1);
    const int width = e_raw - b;
    const int len   = e - b + 1;       // 1..MW

    const float4* aw = (const float4*)attn_w;
    const float4 w0 = aw[l], w1 = aw[64 + l], w2 = aw[128 + l], w3 = aw[192 + l];

    const float4* xr = (const float4*)(x + (size_t)b * DD);
    float* orow = out + (size_t)n * VECW;

    // row b (current regs c*)
    float4 c0 = xr[l], c1 = xr[64 + l], c2 = xr[128 + l], c3 = xr[192 + l];
    nstore(c0, orow + 4*l);                    // b_vec (floats 0..DD)
    nstore(c1, orow + 4*(64 + l));
    nstore(c2, orow + 4*(128 + l));
    nstore(c3, orow + 4*(192 + l));

    float  ssum = 0.0f;
    float4 h0 = {0,0,0,0}, h1 = {0,0,0,0}, h2 = {0,0,0,0}, h3 = {0,0,0,0};
    float4 a0 = {0,0,0,0}, a1 = {0,0,0,0}, a2 = {0,0,0,0}, a3 = {0,0,0,0};

    // pipelined: issue loads of row i while row i-1's dot/reduce/exp chain runs
    for (int i = 1; i < len; ++i) {
        const float4* row = xr + (size_t)i * 256;
        const float4 n0 = row[l], n1 = row[64 + l], n2 = row[128 + l], n3 = row[192 + l];
        PROC_ROW(c0, c1, c2, c3);
        c0 = n0; c1 = n1; c2 = n2; c3 = n3;
    }
    PROC_ROW(c0, c1, c2, c3);                  // last row (== row e)

    float* esec = orow + DD;                   // e_vec (floats DD..2*DD)
    nstore(c0, esec + 4*l);
    nstore(c1, esec + 4*(64 + l));
    nstore(c2, esec + 4*(128 + l));
    nstore(c3, esec + 4*(192 + l));

    const float invs = 1.0f / ssum;
    const float invl = 1.0f / (float)len;
    h0.x *= invs; h0.y *= invs; h0.z *= invs; h0.w *= invs;
    h1.x *= invs; h1.y *= invs; h1.z *= invs; h1.w *= invs;
    h2.x *= invs; h2.y *= invs; h2.z *= invs; h2.w *= invs;
    h3.x *= invs; h3.y *= invs; h3.z *= invs; h3.w *= invs;
    a0.x *= invl; a0.y *= invl; a0.z *= invl; a0.w *= invl;
    a1.x *= invl; a1.y *= invl; a1.z *= invl; a1.w *= invl;
    a2.x *= invl; a2.y *= invl; a2.z *= invl; a2.w *= invl;
    a3.x *= invl; a3.y *= invl; a3.z *= invl; a3.w *= invl;

    float* hsec = orow + 2*DD + WEMB;          // head_emb
    nstore(h0, hsec + 4*l);
    nstore(h1, hsec + 4*(64 + l));
    nstore(h2, hsec + 4*(128 + l));
    nstore(h3, hsec + 4*(192 + l));
    float* asec = orow + 3*DD + WEMB;          // span_avg
    nstore(a0, asec + 4*l);
    nstore(a1, asec + 4*(64 + l));
    nstore(a2, asec + 4*(128 + l));
    nstore(a3, asec + 4*(192 + l));

    if (l < 5) {                               // width_emb: 5 float4 = 20 floats
        const float4 we = ((const float4*)(embed_w + width * WEMB))[l];
        nstore(we, orow + 2*DD + 4*l);
    }
    if (l == 63)
        __builtin_nontemporal_store((float)width, out + (size_t)NSPAN * VECW + n);
}

extern "C" void kernel_launch(void* const* d_in, const int* in_sizes, int n_in,
                              void* d_out, int out_size, void* d_ws, size_t ws_size,
                              hipStream_t stream) {
    const float* x       = (const float*)d_in[0];  // [1,T,D]
    const int*   b       = (const int*)  d_in[1];  // [1,N]
    const int*   e       = (const int*)  d_in[2];  // [1,N]
    const float* embed_w = (const float*)d_in[4];  // [MW,WEMB]
    const float* attn_w  = (const float*)d_in[5];  // [D,1]
    float* out = (float*)d_out;

    int* perm = (int*)d_ws;                        // NSPAN ints

    sort_kernel<<<1, 1024, 0, stream>>>(b, perm);
    span_kernel<<<NSPAN / 4, 256, 0, stream>>>(x, b, e, embed_w, attn_w, perm, out);
}